// Round 5
// baseline (133.585 us; speedup 1.0000x reference)
//
#include <hip/hip_runtime.h>
#include <math.h>

namespace {
constexpr int L = 7, S = 200, SE = 240, D = 32, B = 512;
constexpr int NTOK = L * B;              // 3584
constexpr int NCLUST = L * S;            // 1400
constexpr int NCOMP_BLK = NCLUST / 4;    // 350 compose blocks, wave-per-cluster
constexpr int GRID = 1024;
constexpr int NROUTE_WAVES = (GRID - NCOMP_BLK) * 4;  // 2696 dedicated router waves
constexpr int NCOMP_TOK = NTOK - NROUTE_WAVES;        // 888 tokens routed by compose waves

// Route one token: dots vs 200 centroids, exact top-3 (jax tie-break), softmax,
// relaxed-spin on the 3 cluster flags (NO acquire in the loop — R3's mistake),
// one fence, gather C rows -> out.
__device__ __forceinline__ void route_one(
    const int tok, const int lane,
    const float* __restrict__ x, const float* __restrict__ vc,
    const float* __restrict__ C, const unsigned* __restrict__ flags,
    float* __restrict__ out)
{
  const int l = tok >> 9;  // B = 512
  const int q = lane & 7;  // float4 column
  const int r8 = lane >> 3;

  const float4 xq = reinterpret_cast<const float4*>(x + tok * D)[q];  // one 128B line
  const float* vcl = vc + l * S * D;

  float v0 = -INFINITY, v1 = -INFINITY, v2 = -INFINITY;
  int i0 = 0x7fffffff, i1 = 0x7fffffff, i2 = 0x7fffffff;
  for (int s0 = 0; s0 < S; s0 += 8) {  // 25 iters; wave reads 8 rows x 128B contiguous
    const int row = s0 + r8;
    const float4 v = reinterpret_cast<const float4*>(vcl + row * D)[q];
    float part = v.x * xq.x + v.y * xq.y + v.z * xq.z + v.w * xq.w;
    part += __shfl_xor(part, 1);
    part += __shfl_xor(part, 2);
    part += __shfl_xor(part, 4);
    if (q == 0) {  // strict > keeps earlier (smaller) index; row increases per lane
      if (part > v0) { v2 = v1; i2 = i1; v1 = v0; i1 = i0; v0 = part; i0 = row; }
      else if (part > v1) { v2 = v1; i2 = i1; v1 = part; i1 = row; }
      else if (part > v2) { v2 = part; i2 = row; }
    }
  }
#pragma unroll
  for (int m = 1; m < 64; m <<= 1) {  // butterfly merge (desc value, low index on ties)
    const float u0 = __shfl_xor(v0, m);
    const float u1 = __shfl_xor(v1, m);
    const float u2 = __shfl_xor(v2, m);
    const int j0 = __shfl_xor(i0, m);
    const int j1 = __shfl_xor(i1, m);
    const int j2 = __shfl_xor(i2, m);
#pragma unroll
    for (int t = 0; t < 3; ++t) {
      const float u = (t == 0) ? u0 : (t == 1) ? u1 : u2;
      const int j = (t == 0) ? j0 : (t == 1) ? j1 : j2;
      const bool b0 = (u > v0) || (u == v0 && j < i0);
      const bool b1 = (u > v1) || (u == v1 && j < i1);
      const bool b2 = (u > v2) || (u == v2 && j < i2);
      if (b0) { v2 = v1; i2 = i1; v1 = v0; i1 = i0; v0 = u; i0 = j; }
      else if (b1) { v2 = v1; i2 = i1; v1 = u; i1 = j; }
      else if (b2) { v2 = u; i2 = j; }
    }
  }
  const float e1 = __expf(v1 - v0);
  const float e2 = __expf(v2 - v0);
  const float inv = 1.f / (1.f + e1 + e2);
  const float p0 = inv, p1 = e1 * inv, p2 = e2 * inv;

  // Wait for the 3 needed C rows. RELAXED loads only (no L1-invalidate storm);
  // agent-scope atomics bypass L1 so updates are visible.
  if (lane < 3) {
    const int idx = (lane == 0) ? i0 : (lane == 1) ? i1 : i2;
    while (__hip_atomic_load(&flags[l * S + idx], __ATOMIC_RELAXED,
                             __HIP_MEMORY_SCOPE_AGENT) == 0u) {
      __builtin_amdgcn_s_sleep(2);
    }
  }
  __threadfence();  // single acquire-strength fence after all flags observed

  if (lane < D) {
    const float* Cl = C + l * S * D;
    out[tok * D + lane] = p0 * Cl[i0 * D + lane] +
                          p1 * Cl[i1 * D + lane] +
                          p2 * Cl[i2 * D + lane];
  }
}

// Single fused dispatch.
//  blocks [0, NCOMP_BLK):  wave-per-cluster compose -> C row + release flag,
//                          then each of the first 888 compose waves routes one token.
//  blocks [NCOMP_BLK, GRID): wave-per-token route (2696 tokens).
// One-way dependency + compose blocks first in dispatch order -> deadlock-free
// even under arbitrary scheduling (no co-residency requirement).
__global__ __launch_bounds__(256) void fused_kernel(
    const float* __restrict__ x,     // [L,B,D]
    const float* __restrict__ vc,    // [L,S,D]
    const float* __restrict__ vec,   // [L,S,SE,D]
    const float* __restrict__ gain,  // [L,S,SE,2]
    const int* __restrict__ blk,     // [L,S,SE,2]
    float* __restrict__ C,           // [L*S, D] ws
    unsigned* __restrict__ flags,    // [L*S] ws, zeroed by memsetAsync
    float* __restrict__ out)         // [L,B,D]
{
  const int wave = threadIdx.x >> 6;
  const int lane = threadIdx.x & 63;

  if (blockIdx.x < NCOMP_BLK) {
    // ---------------- compose: one wave per (l,s) ----------------
    __shared__ float wl[4][SE];
    const int ls = blockIdx.x * 4 + wave;
    for (int e = lane; e < SE; e += 64) {
      const float2 g2 = reinterpret_cast<const float2*>(gain)[ls * SE + e];  // 8B contiguous
      const int2 b2 = reinterpret_cast<const int2*>(blk)[ls * SE + e];
      wl[wave][e] = (b2.x != 0) ? 1.0f / (1.0f + __expf(-g2.x)) : 0.0f;
    }
    __syncthreads();
    const int d4 = lane & 7;   // float4 column [0,8)
    const int eg = lane >> 3;  // e-row group [0,8)
    const float4* v4 = reinterpret_cast<const float4*>(vec) + (size_t)ls * SE * 8;
    float4 acc = make_float4(0.f, 0.f, 0.f, 0.f);
#pragma unroll 10
    for (int k = 0; k < 30; ++k) {  // wave reads 8 rows x 128B = 1KB contiguous per step
      const int e = eg + 8 * k;
      const float we = wl[wave][e];
      const float4 v = v4[e * 8 + d4];
      acc.x += we * v.x; acc.y += we * v.y; acc.z += we * v.z; acc.w += we * v.w;
    }
#pragma unroll
    for (int m = 8; m < 64; m <<= 1) {  // reduce over eg (lane bits 3..5)
      acc.x += __shfl_xor(acc.x, m);
      acc.y += __shfl_xor(acc.y, m);
      acc.z += __shfl_xor(acc.z, m);
      acc.w += __shfl_xor(acc.w, m);
    }
    if (eg == 0) reinterpret_cast<float4*>(C + ls * D)[d4] = acc;
    __threadfence();  // make C row visible device-wide before publishing
    if (lane == 0)
      __hip_atomic_store(&flags[ls], 1u, __ATOMIC_RELEASE, __HIP_MEMORY_SCOPE_AGENT);

    // then help route: first 888 compose waves take the tail tokens
    const int g = blockIdx.x * 4 + wave;
    if (g < NCOMP_TOK) route_one(NROUTE_WAVES + g, lane, x, vc, C, flags, out);
  } else {
    // ---------------- route: one wave per token ----------------
    const int g = (blockIdx.x - NCOMP_BLK) * 4 + wave;  // [0, 2696)
    route_one(g, lane, x, vc, C, flags, out);
  }
}

}  // namespace

extern "C" void kernel_launch(void* const* d_in, const int* in_sizes, int n_in,
                              void* d_out, int out_size, void* d_ws, size_t ws_size,
                              hipStream_t stream) {
  const float* x = (const float*)d_in[0];      // [L,B,D]
  const float* vc = (const float*)d_in[1];     // [L,S,D]
  const float* vec = (const float*)d_in[2];    // [L,S,SE,D]
  const float* gain = (const float*)d_in[3];   // [L,S,SE,2]
  const int* blk = (const int*)d_in[4];        // [L,S,SE,2]
  float* out = (float*)d_out;                  // [L,B,D]

  char* ws = (char*)d_ws;
  float* C = (float*)ws;                          // 179,200 B
  unsigned* flags = (unsigned*)(ws + 179200);     // 5,600 B

  hipMemsetAsync(flags, 0, NCLUST * sizeof(unsigned), stream);
  fused_kernel<<<GRID, 256, 0, stream>>>(x, vc, vec, gain, blk, C, flags, out);
}